// Round 5
// baseline (221.348 us; speedup 1.0000x reference)
//
#include <hip/hip_runtime.h>
#include <stdint.h>

// ReconstructionDecoder, factorized, single fused kernel with a MANUAL
// device-scope grid barrier (plain launch; hipLaunchCooperativeKernel hung
// the container under graph capture in r4).
//
// Identity: h = xt[bnt] + f[fi] (broadcast sum), W1g = g*W1:
//   LN(h)@W1 + b1 = rs*( (xt@W1g)[e] + (f@W1g)[e] - mu*G[e] ) + K[e]
//   G[e] = sum_k g_k W1[k,e], K[e] = b1[e] + sum_k b_k W1[k,e],
//   mu = (Sxt+Sf)/256, var = (Sxt2 + 2*(xt.f) + Sf2)/256 - mu^2.
// Phase 1: stats, bf16 hi/lo split A and B operands, GKW table.
// Phase 2: [2176x768]@[768x640] -> U[2048x512], C[2048x128], Vt[512x128]
//          as 1360 independent 16-row wave-tiles, B straight from L2, no LDS.
// Phase 3: packed-f32 broadcast/relu/W2-fold, LDS cross-wave reduce.
//
// Barrier safety: 512 blocks x 256 thr @ __launch_bounds__(256,2) = 2048
// waves = exactly the chip's 8 waves/CU x 256 CU -> ALL blocks co-resident
// (LDS 17.4KB << 80KB/block, VGPR capped at 256), so a spin barrier cannot
// deadlock. Monotonic counter -> correct across graph replays without reset.

#define D_ 256
#define E_ 512
#define NBLK 512

typedef __attribute__((ext_vector_type(8))) short short8;
typedef __attribute__((ext_vector_type(4))) short short4v;
typedef __attribute__((ext_vector_type(4))) float f32x4;
typedef __attribute__((ext_vector_type(2))) float f32x2;

// ---- module-scope scratch (rewritten fully every launch; d_ws untouched) ----
__device__ alignas(16) unsigned short g_Abuf[2176 * 768];  // 3.34 MB
__device__ alignas(16) unsigned short g_Bbuf[768 * 640];   // 0.98 MB
__device__ alignas(16) float g_U[2048 * 512];              // 4 MB
__device__ alignas(16) float g_C[2048 * 128];              // 1 MB
__device__ alignas(16) float g_Vt[512 * 128];              // 256 KB
__device__ alignas(16) float g_GKW[512 * 4];
__device__ alignas(16) float g_sxt[2048];
__device__ alignas(16) float g_sqxt[2048];
__device__ alignas(16) float g_sf[128];
__device__ alignas(16) float g_sqf[128];
__device__ unsigned int g_bar = 0;  // monotonic grid-barrier counter

__device__ inline unsigned short f2bf(float f) {
  unsigned int u = __float_as_uint(f);
  u += 0x7fffu + ((u >> 16) & 1u);
  return (unsigned short)(u >> 16);
}
__device__ inline float bf2f(unsigned short h) {
  return __uint_as_float(((unsigned int)h) << 16);
}

// Monotonic device-scope grid barrier. Requires all NBLK blocks resident.
__device__ inline void grid_barrier() {
  __syncthreads();  // block's stores issued & drained (barrier vmcnt(0))
  if (threadIdx.x == 0) {
    __threadfence();  // release: wb this XCD's L2 to coherence point
    const unsigned old =
        __hip_atomic_fetch_add(&g_bar, 1u, __ATOMIC_RELAXED,
                               __HIP_MEMORY_SCOPE_AGENT);
    const unsigned target = (old & ~(unsigned)(NBLK - 1)) + NBLK;
    while (__hip_atomic_load(&g_bar, __ATOMIC_RELAXED,
                             __HIP_MEMORY_SCOPE_AGENT) < target)
      __builtin_amdgcn_s_sleep(2);
    __threadfence();  // acquire: inv L1 + this XCD's L2
  }
  __syncthreads();
}

__global__ __launch_bounds__(256, 2) void fused(
    const float* __restrict__ x, const float* __restrict__ t_emb,
    const float* __restrict__ f_emb, const float* __restrict__ ln_g,
    const float* __restrict__ ln_b, const float* __restrict__ W1,
    const float* __restrict__ b1, const float* __restrict__ W2,
    const float* __restrict__ b2, float* __restrict__ out) {
  __shared__ float part[4][64][17];  // 17.4 KB (phase 3)
  const int tid = threadIdx.x;
  const int blk = blockIdx.x;   // 0..511
  const int wv = tid >> 6;      // 0..3
  const int lane = tid & 63;
  const int wg = blk * 4 + wv;  // global wave id, 0..2047

  // ================= phase 1: prep (3144 wave-tasks, <=2 per wave) =========
  for (int wt = wg; wt < 3144; wt += 2048) {
    if (wt < 2176) {
      // ---- one row per wave: xt rows [0,2048) then f rows [2048,2176) ----
      const int arow = wt;
      float v0, v1, v2, v3;
      if (arow < 2048) {
        const int bn = arow >> 7, t = arow & 127;
        const float4 xv = *(const float4*)(x + bn * D_ + 4 * lane);
        const float4 tv = *(const float4*)(t_emb + t * D_ + 4 * lane);
        v0 = xv.x + tv.x; v1 = xv.y + tv.y;
        v2 = xv.z + tv.z; v3 = xv.w + tv.w;
      } else {
        const int fi = arow - 2048;
        const float4 fv = *(const float4*)(f_emb + fi * D_ + 4 * lane);
        v0 = fv.x; v1 = fv.y; v2 = fv.z; v3 = fv.w;
      }
      union { unsigned short u[4]; short4v v; } hi, lo;
      hi.u[0] = f2bf(v0); hi.u[1] = f2bf(v1);
      hi.u[2] = f2bf(v2); hi.u[3] = f2bf(v3);
      lo.u[0] = f2bf(v0 - bf2f(hi.u[0]));
      lo.u[1] = f2bf(v1 - bf2f(hi.u[1]));
      lo.u[2] = f2bf(v2 - bf2f(hi.u[2]));
      lo.u[3] = f2bf(v3 - bf2f(hi.u[3]));
      unsigned short* ab = g_Abuf + arow * 768 + 4 * lane;
      *(short4v*)(ab) = hi.v;        // cols [0,256):   hi
      *(short4v*)(ab + 256) = lo.v;  // cols [256,512): lo
      *(short4v*)(ab + 512) = hi.v;  // cols [512,768): hi
      float s = (v0 + v1) + (v2 + v3);
      float q = fmaf(v0, v0, fmaf(v1, v1, fmaf(v2, v2, v3 * v3)));
#pragma unroll
      for (int d = 1; d < 64; d <<= 1) {
        s += __shfl_xor(s, d);
        q += __shfl_xor(q, d);
      }
      if (lane == 0) {
        if (arow < 2048) { g_sxt[arow] = s; g_sqxt[arow] = q; }
        else             { g_sf[arow - 2048] = s; g_sqf[arow - 2048] = q; }
      }
    } else if (wt < 2184) {
      // ---- GKW: 8 waves, wave owns 64 e's, full 256-k column sum ----
      const int e = (wt - 2176) * 64 + lane;
      float G = 0.f, K = 0.f;
#pragma unroll 8
      for (int k = 0; k < 256; ++k) {
        const float wv_ = W1[k * E_ + e];  // coalesced; ln_* are s_loads
        G = fmaf(ln_g[k], wv_, G);
        K = fmaf(ln_b[k], wv_, K);
      }
      float4 o;
      o.x = G; o.y = K + b1[e];
      o.z = W2[2 * e]; o.w = W2[2 * e + 1];
      *(float4*)(g_GKW + 4 * e) = o;
    } else {
      // ---- Bbuf fragments: idx = ((kt*10+ct)*4 + jtl)*64 + lane ----
      const int gidx = (wt - 2184) * 64 + lane;  // 0..61439
      const int gl = gidx & 63;
      const int jtl = (gidx >> 6) & 3;
      const int cc = gidx >> 8;  // 0..239
      const int ct = cc % 10;
      const int kt = cc / 10;    // 0..23
      const int col = ct * 64 + jtl * 16 + (gl & 15);
      const int kbase = kt * 32 + ((gl >> 4) & 3) * 8;
      union { unsigned short u[8]; short8 v; } fr;
#pragma unroll
      for (int j = 0; j < 8; ++j) {
        const int kk = kbase + j;  // stacked-K 0..767
        const int term = kk >> 8;  // 0: hi, 1: hi (x lo-side of A), 2: lo
        const int k = kk & 255;
        float v;
        if (col < 512) v = ln_g[k] * W1[k * E_ + col];
        else           v = f_emb[(col - 512) * D_ + k];
        const unsigned short h = f2bf(v);
        fr.u[j] = (term == 2) ? f2bf(v - bf2f(h)) : h;
      }
      *(short8*)(g_Bbuf + gidx * 8) = fr.v;
    }
  }

  grid_barrier();

  // ================= phase 2: gemm, 1360 independent 16-row wave-tiles =====
  if (wg < 1360) {
    const int quad = (lane >> 4) & 3, n16 = lane & 15;
    const int rt16 = wg / 10, ct = wg % 10;
    const int rowb = rt16 * 16;  // 136 groups x 16 rows = 2176
    const unsigned short* a0 = g_Abuf + (size_t)(rowb + n16) * 768 + quad * 8;

    f32x4 acc[4];
#pragma unroll
    for (int j = 0; j < 4; ++j) acc[j] = (f32x4){0.f, 0.f, 0.f, 0.f};

#pragma unroll 4
    for (int kt = 0; kt < 24; ++kt) {
      const short8 av = *(const short8*)(a0 + kt * 32);
      const short8* bp =
          (const short8*)g_Bbuf + ((kt * 10 + ct) * 4) * 64 + lane;
#pragma unroll
      for (int jtl = 0; jtl < 4; ++jtl)
        acc[jtl] = __builtin_amdgcn_mfma_f32_16x16x32_bf16(av, bp[jtl * 64],
                                                           acc[jtl], 0, 0, 0);
    }

#pragma unroll
    for (int jtl = 0; jtl < 4; ++jtl)
#pragma unroll
      for (int r = 0; r < 4; ++r) {
        const float val = acc[jtl][r];
        const int grow = rowb + quad * 4 + r;      // C/D: row = quad*4+reg
        const int col = ct * 64 + jtl * 16 + n16;  //      col = lane&15
        if (grow < 2048) {
          if (col < 512) g_U[grow * 512 + col] = val;
          else           g_C[grow * 128 + (col - 512)] = val;
        } else if (col < 512) {
          g_Vt[col * 128 + (grow - 2048)] = val;  // transposed store (tiny)
        }
      }
  }

  grid_barrier();

  // ================= phase 3: packed-f32 decode, 4 waves/block =============
  // Block owns 4 rows (bnt0..bnt0+3); wave owns e-slice [128*wv, 128*wv+128);
  // lane owns f-pair {2l, 2l+1} in f32x2 halves.
  {
    const int bnt0 = blk * 4;
    const f32x2 sf2 = *(const f32x2*)(g_sf + 2 * lane);
    const f32x2 sqf2 = *(const f32x2*)(g_sqf + 2 * lane);
    f32x2 Ar[4], Br[4];
#pragma unroll
    for (int ti = 0; ti < 4; ++ti) {
      const float sx = g_sxt[bnt0 + ti];
      const float sqx = g_sqxt[bnt0 + ti];
      const f32x2 c2 = *(const f32x2*)(g_C + (bnt0 + ti) * 128 + 2 * lane);
      const f32x2 mu = (sf2 + sx) * (1.0f / 256.0f);
      const f32x2 var = (sqf2 + 2.0f * c2 + sqx) * (1.0f / 256.0f) - mu * mu;
      f32x2 rs;
      rs.x = rsqrtf(var.x + 1e-5f);
      rs.y = rsqrtf(var.y + 1e-5f);
      Ar[ti] = rs;
      Br[ti] = -rs * mu;
    }

    f32x2 o0[4] = {(f32x2){0.f, 0.f}, (f32x2){0.f, 0.f},
                   (f32x2){0.f, 0.f}, (f32x2){0.f, 0.f}};
    f32x2 o1[4] = {(f32x2){0.f, 0.f}, (f32x2){0.f, 0.f},
                   (f32x2){0.f, 0.f}, (f32x2){0.f, 0.f}};
    const int ebase = __builtin_amdgcn_readfirstlane(wv * 128);
#pragma unroll 8
    for (int ei = 0; ei < 128; ++ei) {
      const int e = ebase + ei;
      const float4 gkw = *(const float4*)(g_GKW + 4 * e);           // s_load
      const f32x2 v2 = *(const f32x2*)(g_Vt + e * 128 + 2 * lane);  // coalesced
#pragma unroll
      for (int ti = 0; ti < 4; ++ti) {
        const float u = g_U[(bnt0 + ti) * 512 + e];  // wave-uniform s_load
        const f32x2 s = v2 + u;                                   // pk_add
        const f32x2 pre = Ar[ti] * s + (Br[ti] * gkw.x + gkw.y);  // pk_fma x2
        f32x2 y;
        y.x = fmaxf(pre.x, 0.f);
        y.y = fmaxf(pre.y, 0.f);
        o0[ti] += y * gkw.z;  // pk_fma
        o1[ti] += y * gkw.w;  // pk_fma
      }
    }

#pragma unroll
    for (int ti = 0; ti < 4; ++ti) {
      part[wv][lane][ti * 4 + 0] = o0[ti].x;  // f even, ch0
      part[wv][lane][ti * 4 + 1] = o1[ti].x;  // f even, ch1
      part[wv][lane][ti * 4 + 2] = o0[ti].y;  // f odd,  ch0
      part[wv][lane][ti * 4 + 3] = o1[ti].y;  // f odd,  ch1
    }
    __syncthreads();

    const int f = tid & 127;
    const int m = f >> 1, ff = f & 1;
#pragma unroll
    for (int t = tid >> 7; t < 4; t += 2) {
      float r0 = b2[0], r1 = b2[1];
#pragma unroll
      for (int w2 = 0; w2 < 4; ++w2) {
        r0 += part[w2][m][t * 4 + ff * 2 + 0];
        r1 += part[w2][m][t * 4 + ff * 2 + 1];
      }
      float2 res;
      res.x = r0;
      res.y = r1;
      *(float2*)(out + ((bnt0 + t) * 128 + f) * 2) = res;
    }
  }
}

// ---------------------------------------------------------------------------
extern "C" void kernel_launch(void* const* d_in, const int* in_sizes, int n_in,
                              void* d_out, int out_size, void* d_ws,
                              size_t ws_size, hipStream_t stream) {
  const float* x = (const float*)d_in[0];
  const float* t_emb = (const float*)d_in[1];
  const float* f_emb = (const float*)d_in[2];
  const float* ln_g = (const float*)d_in[3];
  const float* ln_b = (const float*)d_in[4];
  const float* W1 = (const float*)d_in[5];
  const float* b1 = (const float*)d_in[6];
  const float* W2 = (const float*)d_in[7];
  const float* b2 = (const float*)d_in[8];
  (void)d_ws; (void)ws_size;

  fused<<<NBLK, 256, 0, stream>>>(x, t_emb, f_emb, ln_g, ln_b, W1, b1, W2, b2,
                                  (float*)d_out);
}

// Round 6
// 153.673 us; speedup vs baseline: 1.4404x; 1.4404x over previous
//
#include <hip/hip_runtime.h>
#include <stdint.h>

// ReconstructionDecoder, factorized, TWO kernels, no global sync.
// (r5 lesson: device-scope spin barriers idle ~155us in this harness —
//  the threadfence L2 writeback/invalidate storm serializes everything.)
//
// Identity: h = xt[bnt] + f[fi] (broadcast sum), W1g = g*W1:
//   LN(h)@W1 + b1 = rs*( (xt@W1g)[e] + (f@W1g)[e] - mu*G[e] ) + K[e]
//   G[e] = sum_k g_k W1[k,e], K[e] = b1[e] + sum_k b_k W1[k,e],
//   mu = (Sxt+Sf)/256, var = (Sxt2 + 2*(xt.f) + Sf2)/256 - mu^2.
//
// prep:  xt-row bf16 hi/lo A-frags + stats; f-row stats; GKW; Bbuf frags;
//        Vt[e,f] = f_emb@W1g computed DIRECTLY in f32 VALU (exact, 100 MFLOP).
// fused2: per block (4 rows): mini-GEMM [4x768]@[768x640] -> U|C tile in LDS
//        (rows 4-way replicated in the 16-row MFMA tile), then packed-f32
//        decode: pre = rs*(U+V) - rs*mu*G + K, relu, fold W2, LDS reduce.
//        U/C never touch global memory; one dispatch boundary removed.

#define D_ 256
#define E_ 512

typedef __attribute__((ext_vector_type(8))) short short8;
typedef __attribute__((ext_vector_type(4))) short short4v;
typedef __attribute__((ext_vector_type(4))) float f32x4;
typedef __attribute__((ext_vector_type(2))) float f32x2;

// ---- module-scope scratch (rewritten fully every launch; d_ws untouched) ----
__device__ alignas(16) unsigned short g_Abuf[2048 * 768];  // 3.1 MB
__device__ alignas(16) unsigned short g_Bbuf[768 * 640];   // 0.98 MB
__device__ alignas(16) float g_Vt[512 * 128];              // 256 KB, exact f32
__device__ alignas(16) float g_GKW[512 * 4];
__device__ alignas(16) float g_sxt[2048];
__device__ alignas(16) float g_sqxt[2048];
__device__ alignas(16) float g_sf[128];
__device__ alignas(16) float g_sqf[128];

__device__ inline unsigned short f2bf(float f) {
  unsigned int u = __float_as_uint(f);
  u += 0x7fffu + ((u >> 16) & 1u);
  return (unsigned short)(u >> 16);
}
__device__ inline float bf2f(unsigned short h) {
  return __uint_as_float(((unsigned int)h) << 16);
}

// ---------------------------------------------------------------------------
// prep block roles:
//   [0,512):   xt rows -> Abuf rows 0..2047 as [hi|lo|hi] + Sxt/Sxt2
//   [512,544): f rows  -> Sf/Sf2 only
//   [544,552): GKW[e] = {G, K, W2[e][0], W2[e][1]}, k-split 4 waves
//   [552,792): Bbuf MFMA-fragment-ordered (3-term split-K stacking)
//   [792,920): Vt[e,f] = sum_k g_k W1[k,e] f_emb[f,k], straight f32
// ---------------------------------------------------------------------------
__global__ __launch_bounds__(256) void prep(
    const float* __restrict__ x, const float* __restrict__ t_emb,
    const float* __restrict__ f_emb, const float* __restrict__ ln_g,
    const float* __restrict__ ln_b, const float* __restrict__ W1,
    const float* __restrict__ b1, const float* __restrict__ W2) {
  const int blk = blockIdx.x;
  const int tid = threadIdx.x;
  const int wv = tid >> 6;
  const int l = tid & 63;
  if (blk < 512) {
    // ---- xt rows: 4 rows/block, 1 row/wave ----
    const int r = blk * 4 + wv;  // 0..2047
    const int bn = r >> 7, t = r & 127;
    const float4 xv = *(const float4*)(x + bn * D_ + 4 * l);
    const float4 tv = *(const float4*)(t_emb + t * D_ + 4 * l);
    const float v0 = xv.x + tv.x, v1 = xv.y + tv.y;
    const float v2 = xv.z + tv.z, v3 = xv.w + tv.w;
    union { unsigned short u[4]; short4v v; } hi, lo;
    hi.u[0] = f2bf(v0); hi.u[1] = f2bf(v1);
    hi.u[2] = f2bf(v2); hi.u[3] = f2bf(v3);
    lo.u[0] = f2bf(v0 - bf2f(hi.u[0]));
    lo.u[1] = f2bf(v1 - bf2f(hi.u[1]));
    lo.u[2] = f2bf(v2 - bf2f(hi.u[2]));
    lo.u[3] = f2bf(v3 - bf2f(hi.u[3]));
    unsigned short* ab = g_Abuf + r * 768 + 4 * l;
    *(short4v*)(ab) = hi.v;        // cols [0,256):   hi
    *(short4v*)(ab + 256) = lo.v;  // cols [256,512): lo
    *(short4v*)(ab + 512) = hi.v;  // cols [512,768): hi
    float s = (v0 + v1) + (v2 + v3);
    float q = fmaf(v0, v0, fmaf(v1, v1, fmaf(v2, v2, v3 * v3)));
#pragma unroll
    for (int d = 1; d < 64; d <<= 1) {
      s += __shfl_xor(s, d);
      q += __shfl_xor(q, d);
    }
    if (l == 0) { g_sxt[r] = s; g_sqxt[r] = q; }
  } else if (blk < 544) {
    // ---- f rows: stats only ----
    const int fi = (blk - 512) * 4 + wv;  // 0..127
    const float4 fv = *(const float4*)(f_emb + fi * D_ + 4 * l);
    float s = (fv.x + fv.y) + (fv.z + fv.w);
    float q = fmaf(fv.x, fv.x,
                   fmaf(fv.y, fv.y, fmaf(fv.z, fv.z, fv.w * fv.w)));
#pragma unroll
    for (int d = 1; d < 64; d <<= 1) {
      s += __shfl_xor(s, d);
      q += __shfl_xor(q, d);
    }
    if (l == 0) { g_sf[fi] = s; g_sqf[fi] = q; }
  } else if (blk < 552) {
    // ---- GKW: block owns 64 e's; wave w owns k-range [64w,64w+64) ----
    __shared__ float red[4][64][2];
    const int e = (blk - 544) * 64 + l;
    const int k0 = wv * 64;
    float G = 0.f, K = 0.f;
#pragma unroll 8
    for (int i = 0; i < 64; ++i) {
      const float wval = W1[(k0 + i) * E_ + e];
      G = fmaf(ln_g[k0 + i], wval, G);
      K = fmaf(ln_b[k0 + i], wval, K);
    }
    red[wv][l][0] = G;
    red[wv][l][1] = K;
    __syncthreads();
    if (wv == 0) {
      G = (red[0][l][0] + red[1][l][0]) + (red[2][l][0] + red[3][l][0]);
      K = (red[0][l][1] + red[1][l][1]) + (red[2][l][1] + red[3][l][1]);
      float4 o;
      o.x = G; o.y = K + b1[e];
      o.z = W2[2 * e]; o.w = W2[2 * e + 1];
      *(float4*)(g_GKW + 4 * e) = o;
    }
  } else if (blk < 792) {
    // ---- Bbuf fragments: idx = ((kt*10+ct)*4 + jtl)*64 + lane ----
    const int gidx = (blk - 552) * 256 + tid;  // 0..61439
    const int gl = gidx & 63;
    const int jtl = (gidx >> 6) & 3;
    const int cc = gidx >> 8;  // 0..239
    const int ct = cc % 10;
    const int kt = cc / 10;    // 0..23
    const int col = ct * 64 + jtl * 16 + (gl & 15);
    const int kbase = kt * 32 + ((gl >> 4) & 3) * 8;
    union { unsigned short u[8]; short8 v; } fr;
#pragma unroll
    for (int j = 0; j < 8; ++j) {
      const int kk = kbase + j;  // stacked-K 0..767
      const int term = kk >> 8;  // 0: hi, 1: hi (x lo-side of A), 2: lo
      const int k = kk & 255;
      float v;
      if (col < 512) v = ln_g[k] * W1[k * E_ + col];
      else           v = f_emb[(col - 512) * D_ + k];
      const unsigned short h = f2bf(v);
      fr.u[j] = (term == 2) ? f2bf(v - bf2f(h)) : h;
    }
    *(short8*)(g_Bbuf + gidx * 8) = fr.v;
  } else {
    // ---- Vt: wave owns one e; lane owns f-pair {2l, 2l+1}; exact f32 ----
    const int e = (blk - 792) * 4 + wv;  // 0..511
    const int eu = __builtin_amdgcn_readfirstlane(e);
    const float* f0 = f_emb + (2 * l) * D_;
    const float* f1 = f0 + D_;
    float s0a = 0.f, s0b = 0.f, s1a = 0.f, s1b = 0.f;
#pragma unroll 4
    for (int k = 0; k < 256; k += 4) {
      const float w0 = ln_g[k + 0] * W1[(k + 0) * E_ + eu];
      const float w1 = ln_g[k + 1] * W1[(k + 1) * E_ + eu];
      const float w2 = ln_g[k + 2] * W1[(k + 2) * E_ + eu];
      const float w3 = ln_g[k + 3] * W1[(k + 3) * E_ + eu];
      const float4 fa = *(const float4*)(f0 + k);
      const float4 fb = *(const float4*)(f1 + k);
      s0a = fmaf(w0, fa.x, s0a); s0b = fmaf(w1, fa.y, s0b);
      s0a = fmaf(w2, fa.z, s0a); s0b = fmaf(w3, fa.w, s0b);
      s1a = fmaf(w0, fb.x, s1a); s1b = fmaf(w1, fb.y, s1b);
      s1a = fmaf(w2, fb.z, s1a); s1b = fmaf(w3, fb.w, s1b);
    }
    float2 res;
    res.x = s0a + s0b;
    res.y = s1a + s1b;
    *(float2*)(g_Vt + eu * 128 + 2 * l) = res;
  }
}

// ---------------------------------------------------------------------------
// fused2: block = 4 bnt rows, 512 threads (8 waves), grid 512.
// Phase A: mini-GEMM [4x768]@[768x640] -> UC[4][640] in LDS.
//   Wave w owns 16-col tiles [5w, 5w+5). A-frag rows replicated: lane row =
//   bnt0 + (n16&3); output rows 0..3 land in quad==0 lanes (row=quad*4+r).
// Phase B: decode. Wave w owns e-slice [64w,64w+64); lane owns f-pair
//   {2l,2l+1}. pre = Ar*(U+V) + (Br*G + K) in v_pk_fma_f32; relu; fold W2;
//   cross-wave LDS reduce (stride 17); add b2; coalesced float2 store.
// ---------------------------------------------------------------------------
__global__ __launch_bounds__(512, 4) void fused2(const float* __restrict__ b2,
                                                 float* __restrict__ out) {
  __shared__ float UC[4][648];       // 10.4 KB  (cols 0..511 = U, 512.. = C)
  __shared__ float part[8][64][17];  // 34.8 KB
  const int tid = threadIdx.x;
  const int w = tid >> 6, lane = tid & 63;
  const int quad = (lane >> 4) & 3, n16 = lane & 15;
  const int bnt0 = blockIdx.x * 4;

  // ================= phase A: UC tile via MFMA =============================
  {
    const unsigned short* a0 =
        g_Abuf + (size_t)(bnt0 + (n16 & 3)) * 768 + quad * 8;
    f32x4 acc[5];
#pragma unroll
    for (int j = 0; j < 5; ++j) acc[j] = (f32x4){0.f, 0.f, 0.f, 0.f};
    const int ct0 = w * 5;  // 16-col tile ids [ct0, ct0+5)
#pragma unroll 4
    for (int kt = 0; kt < 24; ++kt) {
      const short8 av = *(const short8*)(a0 + kt * 32);
#pragma unroll
      for (int j = 0; j < 5; ++j) {
        const int c = ct0 + j;  // 0..39
        const short8 bf = ((const short8*)
            g_Bbuf)[((kt * 10 + (c >> 2)) * 4 + (c & 3)) * 64 + lane];
        acc[j] = __builtin_amdgcn_mfma_f32_16x16x32_bf16(av, bf, acc[j], 0, 0, 0);
      }
    }
    if (quad == 0) {  // rows 0..3 of the 16-row tile are the real rows
#pragma unroll
      for (int j = 0; j < 5; ++j)
#pragma unroll
        for (int r = 0; r < 4; ++r) UC[r][(ct0 + j) * 16 + n16] = acc[j][r];
    }
  }
  __syncthreads();

  // ================= phase B: packed-f32 decode ============================
  const f32x2 sf2 = *(const f32x2*)(g_sf + 2 * lane);
  const f32x2 sqf2 = *(const f32x2*)(g_sqf + 2 * lane);
  f32x2 Ar[4], Br[4];
#pragma unroll
  for (int ti = 0; ti < 4; ++ti) {
    const float sx = g_sxt[bnt0 + ti];
    const float sqx = g_sqxt[bnt0 + ti];
    const f32x2 c2 = *(const f32x2*)&UC[ti][512 + 2 * lane];
    const f32x2 mu = (sf2 + sx) * (1.0f / 256.0f);
    const f32x2 var = (sqf2 + 2.0f * c2 + sqx) * (1.0f / 256.0f) - mu * mu;
    f32x2 rs;
    rs.x = rsqrtf(var.x + 1e-5f);
    rs.y = rsqrtf(var.y + 1e-5f);
    Ar[ti] = rs;
    Br[ti] = -rs * mu;
  }

  f32x2 o0[4] = {(f32x2){0.f, 0.f}, (f32x2){0.f, 0.f},
                 (f32x2){0.f, 0.f}, (f32x2){0.f, 0.f}};
  f32x2 o1[4] = {(f32x2){0.f, 0.f}, (f32x2){0.f, 0.f},
                 (f32x2){0.f, 0.f}, (f32x2){0.f, 0.f}};
  const int ebase = __builtin_amdgcn_readfirstlane(w * 64);
#pragma unroll 8
  for (int ei = 0; ei < 64; ++ei) {
    const int e = ebase + ei;
    const float4 gkw = *(const float4*)(g_GKW + 4 * e);           // s_load
    const f32x2 v2 = *(const f32x2*)(g_Vt + e * 128 + 2 * lane);  // coalesced
#pragma unroll
    for (int ti = 0; ti < 4; ++ti) {
      const float u = UC[ti][e];  // LDS broadcast (wave-uniform addr)
      const f32x2 s = v2 + u;                                   // pk_add
      const f32x2 pre = Ar[ti] * s + (Br[ti] * gkw.x + gkw.y);  // pk_fma x2
      f32x2 y;
      y.x = fmaxf(pre.x, 0.f);
      y.y = fmaxf(pre.y, 0.f);
      o0[ti] += y * gkw.z;  // pk_fma
      o1[ti] += y * gkw.w;  // pk_fma
    }
  }

#pragma unroll
  for (int ti = 0; ti < 4; ++ti) {
    part[w][lane][ti * 4 + 0] = o0[ti].x;  // f even, ch0
    part[w][lane][ti * 4 + 1] = o1[ti].x;  // f even, ch1
    part[w][lane][ti * 4 + 2] = o0[ti].y;  // f odd,  ch0
    part[w][lane][ti * 4 + 3] = o1[ti].y;  // f odd,  ch1
  }
  __syncthreads();

  const int t = tid >> 7, f = tid & 127;  // 4 x 128 = 512 threads
  const int m = f >> 1, ff = f & 1;
  float r0 = b2[0], r1 = b2[1];
#pragma unroll
  for (int w2 = 0; w2 < 8; ++w2) {
    r0 += part[w2][m][t * 4 + ff * 2 + 0];
    r1 += part[w2][m][t * 4 + ff * 2 + 1];
  }
  float2 res;
  res.x = r0;
  res.y = r1;
  *(float2*)(out + ((bnt0 + t) * 128 + f) * 2) = res;
}

// ---------------------------------------------------------------------------
extern "C" void kernel_launch(void* const* d_in, const int* in_sizes, int n_in,
                              void* d_out, int out_size, void* d_ws,
                              size_t ws_size, hipStream_t stream) {
  const float* x = (const float*)d_in[0];
  const float* t_emb = (const float*)d_in[1];
  const float* f_emb = (const float*)d_in[2];
  const float* ln_g = (const float*)d_in[3];
  const float* ln_b = (const float*)d_in[4];
  const float* W1 = (const float*)d_in[5];
  const float* b1 = (const float*)d_in[6];
  const float* W2 = (const float*)d_in[7];
  const float* b2 = (const float*)d_in[8];
  (void)d_ws; (void)ws_size;

  prep<<<920, 256, 0, stream>>>(x, t_emb, f_emb, ln_g, ln_b, W1, b1, W2);
  fused2<<<512, 512, 0, stream>>>(b2, (float*)d_out);
}

// Round 7
// 152.454 us; speedup vs baseline: 1.4519x; 1.0080x over previous
//
#include <hip/hip_runtime.h>
#include <stdint.h>

// ReconstructionDecoder, factorized, TWO kernels, no global sync.
// r5 lesson: no device-scope spin barriers (threadfence storm = ~155us idle).
// r6 lesson: __launch_bounds__(512,4) capped VGPR at 64 -> phase-A loads
//   serialized on L2 latency (62us). Fix: (512,2) -> 128 VGPR, and 8 rows
//   per block (grid 256) to halve the redundant B re-read (512->256 MB).
//
// Identity: h = xt[bnt] + f[fi] (broadcast sum), W1g = g*W1:
//   LN(h)@W1 + b1 = rs*( (xt@W1g)[e] + (f@W1g)[e] - mu*G[e] ) + K[e]
//   G[e] = sum_k g_k W1[k,e], K[e] = b1[e] + sum_k b_k W1[k,e],
//   mu = (Sxt+Sf)/256, var = (Sxt2 + 2*(xt.f) + Sf2)/256 - mu^2.
//
// prep:  xt-row bf16 hi/lo A-frags + stats; f-row stats; GKW; Bbuf frags;
//        Vt[e,f] = f_emb@W1g directly in f32 VALU (exact).
// fused2: per block (8 rows): mini-GEMM [8x768]@[768x640] -> U|C in LDS
//        (rows 2x replicated in the 16-row MFMA tile), then packed-f32
//        decode: pre = rs*(U+V) - rs*mu*G + K, relu, fold W2, LDS reduce.
//        U/C never touch global; part-buffer aliases the UC LDS.

#define D_ 256
#define E_ 512

typedef __attribute__((ext_vector_type(8))) short short8;
typedef __attribute__((ext_vector_type(4))) short short4v;
typedef __attribute__((ext_vector_type(4))) float f32x4;
typedef __attribute__((ext_vector_type(2))) float f32x2;

// ---- module-scope scratch (rewritten fully every launch; d_ws untouched) ----
__device__ alignas(16) unsigned short g_Abuf[2048 * 768];  // 3.1 MB
__device__ alignas(16) unsigned short g_Bbuf[768 * 640];   // 0.98 MB
__device__ alignas(16) float g_Vt[512 * 128];              // 256 KB, exact f32
__device__ alignas(16) float g_GKW[512 * 4];
__device__ alignas(16) float g_sxt[2048];
__device__ alignas(16) float g_sqxt[2048];
__device__ alignas(16) float g_sf[128];
__device__ alignas(16) float g_sqf[128];

__device__ inline unsigned short f2bf(float f) {
  unsigned int u = __float_as_uint(f);
  u += 0x7fffu + ((u >> 16) & 1u);
  return (unsigned short)(u >> 16);
}
__device__ inline float bf2f(unsigned short h) {
  return __uint_as_float(((unsigned int)h) << 16);
}

// ---------------------------------------------------------------------------
// prep block roles:
//   [0,512):   xt rows -> Abuf rows 0..2047 as [hi|lo|hi] + Sxt/Sxt2
//   [512,544): f rows  -> Sf/Sf2 only
//   [544,552): GKW[e] = {G, K, W2[e][0], W2[e][1]}, k-split 4 waves
//   [552,792): Bbuf MFMA-fragment-ordered (3-term split-K stacking)
//   [792,920): Vt[e,f] = sum_k g_k W1[k,e] f_emb[f,k], straight f32
// ---------------------------------------------------------------------------
__global__ __launch_bounds__(256) void prep(
    const float* __restrict__ x, const float* __restrict__ t_emb,
    const float* __restrict__ f_emb, const float* __restrict__ ln_g,
    const float* __restrict__ ln_b, const float* __restrict__ W1,
    const float* __restrict__ b1, const float* __restrict__ W2) {
  const int blk = blockIdx.x;
  const int tid = threadIdx.x;
  const int wv = tid >> 6;
  const int l = tid & 63;
  if (blk < 512) {
    // ---- xt rows: 4 rows/block, 1 row/wave ----
    const int r = blk * 4 + wv;  // 0..2047
    const int bn = r >> 7, t = r & 127;
    const float4 xv = *(const float4*)(x + bn * D_ + 4 * l);
    const float4 tv = *(const float4*)(t_emb + t * D_ + 4 * l);
    const float v0 = xv.x + tv.x, v1 = xv.y + tv.y;
    const float v2 = xv.z + tv.z, v3 = xv.w + tv.w;
    union { unsigned short u[4]; short4v v; } hi, lo;
    hi.u[0] = f2bf(v0); hi.u[1] = f2bf(v1);
    hi.u[2] = f2bf(v2); hi.u[3] = f2bf(v3);
    lo.u[0] = f2bf(v0 - bf2f(hi.u[0]));
    lo.u[1] = f2bf(v1 - bf2f(hi.u[1]));
    lo.u[2] = f2bf(v2 - bf2f(hi.u[2]));
    lo.u[3] = f2bf(v3 - bf2f(hi.u[3]));
    unsigned short* ab = g_Abuf + r * 768 + 4 * l;
    *(short4v*)(ab) = hi.v;        // cols [0,256):   hi
    *(short4v*)(ab + 256) = lo.v;  // cols [256,512): lo
    *(short4v*)(ab + 512) = hi.v;  // cols [512,768): hi
    float s = (v0 + v1) + (v2 + v3);
    float q = fmaf(v0, v0, fmaf(v1, v1, fmaf(v2, v2, v3 * v3)));
#pragma unroll
    for (int d = 1; d < 64; d <<= 1) {
      s += __shfl_xor(s, d);
      q += __shfl_xor(q, d);
    }
    if (l == 0) { g_sxt[r] = s; g_sqxt[r] = q; }
  } else if (blk < 544) {
    // ---- f rows: stats only ----
    const int fi = (blk - 512) * 4 + wv;  // 0..127
    const float4 fv = *(const float4*)(f_emb + fi * D_ + 4 * l);
    float s = (fv.x + fv.y) + (fv.z + fv.w);
    float q = fmaf(fv.x, fv.x,
                   fmaf(fv.y, fv.y, fmaf(fv.z, fv.z, fv.w * fv.w)));
#pragma unroll
    for (int d = 1; d < 64; d <<= 1) {
      s += __shfl_xor(s, d);
      q += __shfl_xor(q, d);
    }
    if (l == 0) { g_sf[fi] = s; g_sqf[fi] = q; }
  } else if (blk < 552) {
    // ---- GKW: block owns 64 e's; wave w owns k-range [64w,64w+64) ----
    __shared__ float red[4][64][2];
    const int e = (blk - 544) * 64 + l;
    const int k0 = wv * 64;
    float G = 0.f, K = 0.f;
#pragma unroll 8
    for (int i = 0; i < 64; ++i) {
      const float wval = W1[(k0 + i) * E_ + e];
      G = fmaf(ln_g[k0 + i], wval, G);
      K = fmaf(ln_b[k0 + i], wval, K);
    }
    red[wv][l][0] = G;
    red[wv][l][1] = K;
    __syncthreads();
    if (wv == 0) {
      G = (red[0][l][0] + red[1][l][0]) + (red[2][l][0] + red[3][l][0]);
      K = (red[0][l][1] + red[1][l][1]) + (red[2][l][1] + red[3][l][1]);
      float4 o;
      o.x = G; o.y = K + b1[e];
      o.z = W2[2 * e]; o.w = W2[2 * e + 1];
      *(float4*)(g_GKW + 4 * e) = o;
    }
  } else if (blk < 792) {
    // ---- Bbuf fragments: idx = ((kt*10+ct)*4 + jtl)*64 + lane ----
    const int gidx = (blk - 552) * 256 + tid;  // 0..61439
    const int gl = gidx & 63;
    const int jtl = (gidx >> 6) & 3;
    const int cc = gidx >> 8;  // 0..239
    const int ct = cc % 10;
    const int kt = cc / 10;    // 0..23
    const int col = ct * 64 + jtl * 16 + (gl & 15);
    const int kbase = kt * 32 + ((gl >> 4) & 3) * 8;
    union { unsigned short u[8]; short8 v; } fr;
#pragma unroll
    for (int j = 0; j < 8; ++j) {
      const int kk = kbase + j;  // stacked-K 0..767
      const int term = kk >> 8;  // 0: hi, 1: hi (x lo-side of A), 2: lo
      const int k = kk & 255;
      float v;
      if (col < 512) v = ln_g[k] * W1[k * E_ + col];
      else           v = f_emb[(col - 512) * D_ + k];
      const unsigned short h = f2bf(v);
      fr.u[j] = (term == 2) ? f2bf(v - bf2f(h)) : h;
    }
    *(short8*)(g_Bbuf + gidx * 8) = fr.v;
  } else {
    // ---- Vt: wave owns one e; lane owns f-pair {2l, 2l+1}; exact f32 ----
    const int e = (blk - 792) * 4 + wv;  // 0..511
    const int eu = __builtin_amdgcn_readfirstlane(e);
    const float* f0 = f_emb + (2 * l) * D_;
    const float* f1 = f0 + D_;
    float s0a = 0.f, s0b = 0.f, s1a = 0.f, s1b = 0.f;
#pragma unroll 4
    for (int k = 0; k < 256; k += 4) {
      const float w0 = ln_g[k + 0] * W1[(k + 0) * E_ + eu];
      const float w1 = ln_g[k + 1] * W1[(k + 1) * E_ + eu];
      const float w2 = ln_g[k + 2] * W1[(k + 2) * E_ + eu];
      const float w3 = ln_g[k + 3] * W1[(k + 3) * E_ + eu];
      const float4 fa = *(const float4*)(f0 + k);
      const float4 fb = *(const float4*)(f1 + k);
      s0a = fmaf(w0, fa.x, s0a); s0b = fmaf(w1, fa.y, s0b);
      s0a = fmaf(w2, fa.z, s0a); s0b = fmaf(w3, fa.w, s0b);
      s1a = fmaf(w0, fb.x, s1a); s1b = fmaf(w1, fb.y, s1b);
      s1a = fmaf(w2, fb.z, s1a); s1b = fmaf(w3, fb.w, s1b);
    }
    float2 res;
    res.x = s0a + s0b;
    res.y = s1a + s1b;
    *(float2*)(g_Vt + eu * 128 + 2 * l) = res;
  }
}

// ---------------------------------------------------------------------------
// fused2: block = 8 bnt rows, 512 threads (8 waves), grid 256.
// Phase A: mini-GEMM [8x768]@[768x640] -> UC[8][648] in LDS.
//   A rows 2x replicated: lane row = bnt0 + (n16&7); output row quad*4+r,
//   quads 0..1 hold the 8 real rows. Wave w owns 16-col tiles [5w, 5w+5).
// Phase B: decode. Wave w owns e-slice [64w,64w+64); lane owns f-pair
//   {2l,2l+1}. pre = Ar*(U+V) + (Br*G + K) in v_pk_fma_f32; relu; fold W2.
// part[8][64][33] (67.6KB) ALIASES the UC buffer (time-separated by sync).
// ---------------------------------------------------------------------------
__global__ __launch_bounds__(512, 2) void fused2(const float* __restrict__ b2,
                                                 float* __restrict__ out) {
  __shared__ float smem[8 * 64 * 33];  // 67.6 KB
  float (*part)[64][33] = reinterpret_cast<float (*)[64][33]>(smem);
  float (*UC)[648] = reinterpret_cast<float (*)[648]>(smem);

  const int tid = threadIdx.x;
  const int w = tid >> 6, lane = tid & 63;
  const int quad = (lane >> 4) & 3, n16 = lane & 15;
  const int bnt0 = blockIdx.x * 8;

  // ================= phase A: UC tile via MFMA =============================
  {
    const unsigned short* a0 =
        g_Abuf + (size_t)(bnt0 + (n16 & 7)) * 768 + quad * 8;
    f32x4 acc[5];
#pragma unroll
    for (int j = 0; j < 5; ++j) acc[j] = (f32x4){0.f, 0.f, 0.f, 0.f};
    const int ct0 = w * 5;  // 16-col tile ids [ct0, ct0+5)
#pragma unroll 4
    for (int kt = 0; kt < 24; ++kt) {
      const short8 av = *(const short8*)(a0 + kt * 32);
#pragma unroll
      for (int j = 0; j < 5; ++j) {
        const int c = ct0 + j;  // 0..39
        const short8 bf = ((const short8*)
            g_Bbuf)[((kt * 10 + (c >> 2)) * 4 + (c & 3)) * 64 + lane];
        acc[j] = __builtin_amdgcn_mfma_f32_16x16x32_bf16(av, bf, acc[j], 0, 0, 0);
      }
    }
    if (quad < 2) {  // rows 0..7 of the 16-row tile are the real rows
#pragma unroll
      for (int j = 0; j < 5; ++j)
#pragma unroll
        for (int r = 0; r < 4; ++r)
          UC[quad * 4 + r][(ct0 + j) * 16 + n16] = acc[j][r];
    }
  }
  __syncthreads();

  // ================= phase B: packed-f32 decode ============================
  const f32x2 sf2 = *(const f32x2*)(g_sf + 2 * lane);
  const f32x2 sqf2 = *(const f32x2*)(g_sqf + 2 * lane);
  f32x2 Ar[8], Br[8];
#pragma unroll
  for (int ti = 0; ti < 8; ++ti) {
    const float sx = g_sxt[bnt0 + ti];
    const float sqx = g_sqxt[bnt0 + ti];
    const f32x2 c2 = *(const f32x2*)&UC[ti][512 + 2 * lane];
    const f32x2 mu = (sf2 + sx) * (1.0f / 256.0f);
    const f32x2 var = (sqf2 + 2.0f * c2 + sqx) * (1.0f / 256.0f) - mu * mu;
    f32x2 rs;
    rs.x = rsqrtf(var.x + 1e-5f);
    rs.y = rsqrtf(var.y + 1e-5f);
    Ar[ti] = rs;
    Br[ti] = -rs * mu;
  }

  f32x2 o0[8], o1[8];
#pragma unroll
  for (int ti = 0; ti < 8; ++ti) {
    o0[ti] = (f32x2){0.f, 0.f};
    o1[ti] = (f32x2){0.f, 0.f};
  }
  const int ebase = __builtin_amdgcn_readfirstlane(w * 64);
#pragma unroll 2
  for (int ei = 0; ei < 64; ++ei) {
    const int e = ebase + ei;
    const float4 gkw = *(const float4*)(g_GKW + 4 * e);           // s_load
    const f32x2 v2 = *(const f32x2*)(g_Vt + e * 128 + 2 * lane);  // coalesced
#pragma unroll
    for (int ti = 0; ti < 8; ++ti) {
      const float u = UC[ti][e];  // LDS broadcast (wave-uniform addr)
      const f32x2 s = v2 + u;                                   // pk_add
      const f32x2 pre = Ar[ti] * s + (Br[ti] * gkw.x + gkw.y);  // pk_fma x2
      f32x2 y;
      y.x = fmaxf(pre.x, 0.f);
      y.y = fmaxf(pre.y, 0.f);
      o0[ti] += y * gkw.z;  // pk_fma
      o1[ti] += y * gkw.w;  // pk_fma
    }
  }
  __syncthreads();  // all UC reads done before part overwrites the alias

#pragma unroll
  for (int ti = 0; ti < 8; ++ti) {
    part[w][lane][ti * 4 + 0] = o0[ti].x;  // f even, ch0
    part[w][lane][ti * 4 + 1] = o1[ti].x;  // f even, ch1
    part[w][lane][ti * 4 + 2] = o0[ti].y;  // f odd,  ch0
    part[w][lane][ti * 4 + 3] = o1[ti].y;  // f odd,  ch1
  }
  __syncthreads();

  // cross-wave e-reduce: thread handles rows {tp, tp+4} for its f
  const int f = tid & 127;
  const int tp = tid >> 7;  // 0..3
  const int m = f >> 1, fe = f & 1;
#pragma unroll
  for (int rr = 0; rr < 2; ++rr) {
    const int row = tp + rr * 4;  // 0..7
    float r0 = b2[0], r1 = b2[1];
#pragma unroll
    for (int w2 = 0; w2 < 8; ++w2) {
      r0 += part[w2][m][row * 4 + fe * 2 + 0];
      r1 += part[w2][m][row * 4 + fe * 2 + 1];
    }
    float2 res;
    res.x = r0;
    res.y = r1;
    *(float2*)(out + ((bnt0 + row) * 128 + f) * 2) = res;
  }
}

// ---------------------------------------------------------------------------
extern "C" void kernel_launch(void* const* d_in, const int* in_sizes, int n_in,
                              void* d_out, int out_size, void* d_ws,
                              size_t ws_size, hipStream_t stream) {
  const float* x = (const float*)d_in[0];
  const float* t_emb = (const float*)d_in[1];
  const float* f_emb = (const float*)d_in[2];
  const float* ln_g = (const float*)d_in[3];
  const float* ln_b = (const float*)d_in[4];
  const float* W1 = (const float*)d_in[5];
  const float* b1 = (const float*)d_in[6];
  const float* W2 = (const float*)d_in[7];
  const float* b2 = (const float*)d_in[8];
  (void)d_ws; (void)ws_size;

  prep<<<920, 256, 0, stream>>>(x, t_emb, f_emb, ln_g, ln_b, W1, b1, W2);
  fused2<<<256, 512, 0, stream>>>(b2, (float*)d_out);
}

// Round 9
// 114.632 us; speedup vs baseline: 1.9309x; 1.3299x over previous
//
#include <hip/hip_runtime.h>
#include <stdint.h>

// ReconstructionDecoder, factorized, THREE kernels (r3 structure, proven).
// r5 lesson: no device-scope spin barriers. r6/r7 lesson: fusion spills.
// r8 lesson: sF[128][33] rows were 132B (not 16B-aligned); float4 cast made
//   the compiler emit misaligned ds_write_b128 -> LDS fault -> container
//   death. Fixed: sF[128][36] (144B rows, 16B-aligned slots).
// r8 theory (unfalsified): prep was ~45us because the per-iteration 256MB
//   poison-fill cold-evicts all caches and the Bbuf role did scattered
//   4B-per-64B-line W1 gathers at ~1-2 loads in flight. Now: 48 LDS-staged
//   blocks stream W1/f_emb slabs coalesced (float4, full MLP), emit the
//   MFMA-ordered fragments from LDS. Fragment bytes bitwise identical.
//
// Identity: h = xt[bnt] + f[fi] (broadcast sum), W1g = g*W1:
//   LN(h)@W1 + b1 = rs*( (xt@W1g)[e] + (f@W1g)[e] - mu*G[e] ) + K[e]
//   G[e] = sum_k g_k W1[k,e], K[e] = b1[e] + sum_k b_k W1[k,e],
//   mu = (Sxt+Sf)/256, var = (Sxt2 + 2*(xt.f) + Sf2)/256 - mu^2.

#define D_ 256
#define E_ 512

typedef __attribute__((ext_vector_type(8))) short short8;
typedef __attribute__((ext_vector_type(4))) short short4v;
typedef __attribute__((ext_vector_type(4))) float f32x4;
typedef __attribute__((ext_vector_type(2))) float f32x2;

// ---- module-scope scratch (rewritten fully every launch; d_ws untouched) ----
__device__ alignas(16) unsigned short g_Abuf[2176 * 768];  // 3.34 MB
__device__ alignas(16) unsigned short g_Bbuf[768 * 640];   // 0.98 MB
__device__ alignas(16) float g_U[2048 * 512];              // 4 MB
__device__ alignas(16) float g_C[2048 * 128];              // 1 MB
__device__ alignas(16) float g_Vt[512 * 128];              // 256 KB
__device__ alignas(16) float g_GKW[512 * 4];
__device__ alignas(16) float g_sxt[2048];
__device__ alignas(16) float g_sqxt[2048];
__device__ alignas(16) float g_sf[128];
__device__ alignas(16) float g_sqf[128];

__device__ inline unsigned short f2bf(float f) {
  unsigned int u = __float_as_uint(f);
  u += 0x7fffu + ((u >> 16) & 1u);
  return (unsigned short)(u >> 16);
}
__device__ inline float bf2f(unsigned short h) {
  return __uint_as_float(((unsigned int)h) << 16);
}

// ---------------------------------------------------------------------------
// prep block roles (grid 600):
//   [0,512):   xt rows -> Abuf rows 0..2047 as [hi|lo|hi] + Sxt/Sxt2
//   [512,544): f rows  -> Abuf rows 2048..2175 as [hi|lo|hi] + Sf/Sf2
//   [544,552): GKW[e] = {G, K, W2[e][0], W2[e][1]}, k-split 4 waves
//   [552,600): Bbuf fragments via LDS-staged coalesced W1/f_emb slabs.
//              b = blk-552: kt = b>>1 (0..23), h = b&1 (W1 col-half).
//              term = kt>>3 (0,1: hi; 2: lo), k0 = (kt&7)*32.
// ---------------------------------------------------------------------------
__global__ __launch_bounds__(256) void prep(
    const float* __restrict__ x, const float* __restrict__ t_emb,
    const float* __restrict__ f_emb, const float* __restrict__ ln_g,
    const float* __restrict__ ln_b, const float* __restrict__ W1,
    const float* __restrict__ b1, const float* __restrict__ W2) {
  __shared__ float sW[32][264];  // 33.8 KB; 264*4=1056B rows (16B-aligned)
  __shared__ float sF[128][36];  // 18.0 KB; 36*4=144B rows (16B-aligned!)
  __shared__ float sg[32];
  __shared__ float red[4][64][2];

  const int blk = blockIdx.x;
  const int tid = threadIdx.x;
  const int wv = tid >> 6;
  const int l = tid & 63;

  if (blk < 544) {
    // ---- rows: 4 rows/block, 1 row/wave ----
    int arow;
    float v0, v1, v2, v3;
    if (blk < 512) {
      const int r = blk * 4 + wv;  // 0..2047
      const int bn = r >> 7, t = r & 127;
      const float4 xv = *(const float4*)(x + bn * D_ + 4 * l);
      const float4 tv = *(const float4*)(t_emb + t * D_ + 4 * l);
      v0 = xv.x + tv.x; v1 = xv.y + tv.y;
      v2 = xv.z + tv.z; v3 = xv.w + tv.w;
      arow = r;
    } else {
      const int fi = (blk - 512) * 4 + wv;  // 0..127
      const float4 fv = *(const float4*)(f_emb + fi * D_ + 4 * l);
      v0 = fv.x; v1 = fv.y; v2 = fv.z; v3 = fv.w;
      arow = 2048 + fi;
    }
    union { unsigned short u[4]; short4v v; } hi, lo;
    hi.u[0] = f2bf(v0); hi.u[1] = f2bf(v1);
    hi.u[2] = f2bf(v2); hi.u[3] = f2bf(v3);
    lo.u[0] = f2bf(v0 - bf2f(hi.u[0]));
    lo.u[1] = f2bf(v1 - bf2f(hi.u[1]));
    lo.u[2] = f2bf(v2 - bf2f(hi.u[2]));
    lo.u[3] = f2bf(v3 - bf2f(hi.u[3]));
    unsigned short* ab = g_Abuf + arow * 768 + 4 * l;
    *(short4v*)(ab) = hi.v;        // cols [0,256):   hi
    *(short4v*)(ab + 256) = lo.v;  // cols [256,512): lo
    *(short4v*)(ab + 512) = hi.v;  // cols [512,768): hi
    float s = (v0 + v1) + (v2 + v3);
    float q = fmaf(v0, v0, fmaf(v1, v1, fmaf(v2, v2, v3 * v3)));
#pragma unroll
    for (int d = 1; d < 64; d <<= 1) {
      s += __shfl_xor(s, d);
      q += __shfl_xor(q, d);
    }
    if (l == 0) {
      if (arow < 2048) { g_sxt[arow] = s; g_sqxt[arow] = q; }
      else             { g_sf[arow - 2048] = s; g_sqf[arow - 2048] = q; }
    }
  } else if (blk < 552) {
    // ---- GKW: block owns 64 e's; wave w owns k-range [64w,64w+64) ----
    const int e = (blk - 544) * 64 + l;
    const int k0 = wv * 64;
    float G = 0.f, K = 0.f;
#pragma unroll 8
    for (int i = 0; i < 64; ++i) {
      const float wval = W1[(k0 + i) * E_ + e];
      G = fmaf(ln_g[k0 + i], wval, G);
      K = fmaf(ln_b[k0 + i], wval, K);
    }
    red[wv][l][0] = G;
    red[wv][l][1] = K;
    __syncthreads();
    if (wv == 0) {
      G = (red[0][l][0] + red[1][l][0]) + (red[2][l][0] + red[3][l][0]);
      K = (red[0][l][1] + red[1][l][1]) + (red[2][l][1] + red[3][l][1]);
      float4 o;
      o.x = G; o.y = K + b1[e];
      o.z = W2[2 * e]; o.w = W2[2 * e + 1];
      *(float4*)(g_GKW + 4 * e) = o;
    }
  } else {
    // ---- Bbuf via LDS-staged coalesced slabs ----
    const int b = blk - 552;         // 0..47
    const int kt = b >> 1, h = b & 1;
    const int term = kt >> 3;        // 0,1: hi; 2: lo
    const int k0 = (kt & 7) * 32;
    // stage W1[k0+kk2][256h + c] (kk2<32, c<256): 2048 float4, coalesced
    {
      const float4* w4 = (const float4*)(W1 + (size_t)k0 * E_ + h * 256);
      for (int i = tid; i < 2048; i += 256) {
        const int kk2 = i >> 6, c4 = i & 63;
        *(float4*)&sW[kk2][c4 * 4] = w4[kk2 * (E_ / 4) + c4];
      }
      if (tid < 32) sg[tid] = ln_g[k0 + tid];
      if (h == 0) {  // stage f_emb[f][k0..k0+32): 1024 float4
        const float4* f4 = (const float4*)(f_emb + k0);
        for (int i = tid; i < 1024; i += 256) {
          const int fr = i >> 3, c4 = i & 7;
          *(float4*)&sF[fr][c4 * 4] = f4[fr * (D_ / 4) + c4];
        }
      }
    }
    __syncthreads();
    // emit W1-derived fragments: ct = 4h..4h+3, 1024 frags (4/thread)
    for (int fi = tid; fi < 1024; fi += 256) {
      const int ct = 4 * h + (fi >> 8);
      const int rem = fi & 255;
      const int jtl = rem >> 6, ln = rem & 63;
      const int colw = (ct - 4 * h) * 64 + jtl * 16 + (ln & 15);  // 0..255
      const int kb = ((ln >> 4) & 3) * 8;
      union { unsigned short u[8]; short8 v; } fr8;
#pragma unroll
      for (int j = 0; j < 8; ++j) {
        const float v = sg[kb + j] * sW[kb + j][colw];
        const unsigned short hv = f2bf(v);
        fr8.u[j] = (term == 2) ? f2bf(v - bf2f(hv)) : hv;
      }
      const int gidx = ((kt * 10 + ct) * 4 + jtl) * 64 + ln;
      *(short8*)(g_Bbuf + gidx * 8) = fr8.v;
    }
    if (h == 0) {
      // f_emb-derived fragments: ct 8,9, 512 frags (2/thread)
      for (int fi = tid; fi < 512; fi += 256) {
        const int ct = 8 + (fi >> 8);
        const int rem = fi & 255;
        const int jtl = rem >> 6, ln = rem & 63;
        const int f = (ct - 8) * 64 + jtl * 16 + (ln & 15);  // 0..127
        const int kb = ((ln >> 4) & 3) * 8;
        union { unsigned short u[8]; short8 v; } fr8;
#pragma unroll
        for (int j = 0; j < 8; ++j) {
          const float v = sF[f][kb + j];
          const unsigned short hv = f2bf(v);
          fr8.u[j] = (term == 2) ? f2bf(v - bf2f(hv)) : hv;
        }
        const int gidx = ((kt * 10 + ct) * 4 + jtl) * 64 + ln;
        *(short8*)(g_Bbuf + gidx * 8) = fr8.v;
      }
    }
  }
}

// ---------------------------------------------------------------------------
// gemm3 (r3-proven): [2176 x 768] @ [768 x 640], 128x64 tiles, grid 17x10.
// B fragments MFMA-ordered, L2-resident: straight global->VGPR, no LDS,
// no barriers. Output: rt<16,ct<8 -> U; rt<16,ct>=8 -> C; rt==16,ct<8 -> Vt.
// ---------------------------------------------------------------------------
__global__ __launch_bounds__(256) void gemm3() {
  const int tid = threadIdx.x;
  const int wave = tid >> 6, lane = tid & 63;
  const int quad = (lane >> 4) & 3, n16 = lane & 15;
  const int rt = blockIdx.x / 10, ct = blockIdx.x % 10;
  const int rowb = rt * 128 + wave * 32;

  const unsigned short* a0 = g_Abuf + (size_t)(rowb + n16) * 768 + quad * 8;
  const unsigned short* a1 = a0 + 16 * 768;

  f32x4 acc[2][4];
#pragma unroll
  for (int j = 0; j < 4; ++j) {
    acc[0][j] = (f32x4){0.f, 0.f, 0.f, 0.f};
    acc[1][j] = (f32x4){0.f, 0.f, 0.f, 0.f};
  }

#pragma unroll 4
  for (int kt = 0; kt < 24; ++kt) {
    const short8 av0 = *(const short8*)(a0 + kt * 32);
    const short8 av1 = *(const short8*)(a1 + kt * 32);
    const short8* bp = (const short8*)g_Bbuf + ((kt * 10 + ct) * 4) * 64 + lane;
#pragma unroll
    for (int jtl = 0; jtl < 4; ++jtl) {
      const short8 bf = bp[jtl * 64];
      acc[0][jtl] =
          __builtin_amdgcn_mfma_f32_16x16x32_bf16(av0, bf, acc[0][jtl], 0, 0, 0);
      acc[1][jtl] =
          __builtin_amdgcn_mfma_f32_16x16x32_bf16(av1, bf, acc[1][jtl], 0, 0, 0);
    }
  }

#pragma unroll
  for (int g = 0; g < 2; ++g)
#pragma unroll
    for (int jtl = 0; jtl < 4; ++jtl)
#pragma unroll
      for (int r = 0; r < 4; ++r) {
        const float val = acc[g][jtl][r];
        const int grow = rowb + g * 16 + quad * 4 + r;  // C/D: row=quad*4+reg
        const int col = ct * 64 + jtl * 16 + n16;        //      col=lane&15
        if (rt < 16) {
          if (ct < 8) g_U[grow * 512 + col] = val;
          else        g_C[grow * 128 + (col - 512)] = val;
        } else if (ct < 8) {
          g_Vt[col * 128 + (grow - 2048)] = val;  // transposed store (tiny)
        }
      }
}

// ---------------------------------------------------------------------------
// decode2 (r3-proven): packed-f32 VALU pass. Block = 4 rows, 8 waves.
// Wave w owns e-slice [64w,64w+64); lane owns f-pair {2l,2l+1} as f32x2.
// pre = Ar*(U+V) + (Br*G + K) via v_pk_fma_f32; relu; fold W2; LDS reduce.
// ---------------------------------------------------------------------------
__global__ __launch_bounds__(512) void decode2(const float* __restrict__ b2,
                                               float* __restrict__ out) {
  __shared__ float part[8][64][17];  // 34.8KB partials
  const int tid = threadIdx.x;
  const int w = tid >> 6, lane = tid & 63;
  const int bnt0 = blockIdx.x * 4;

  const f32x2 sf2 = *(const f32x2*)(g_sf + 2 * lane);
  const f32x2 sqf2 = *(const f32x2*)(g_sqf + 2 * lane);
  f32x2 Ar[4], Br[4];
#pragma unroll
  for (int ti = 0; ti < 4; ++ti) {
    const float sx = g_sxt[bnt0 + ti];
    const float sqx = g_sqxt[bnt0 + ti];
    const f32x2 c2 = *(const f32x2*)(g_C + (bnt0 + ti) * 128 + 2 * lane);
    const f32x2 mu = (sf2 + sx) * (1.0f / 256.0f);
    const f32x2 var = (sqf2 + 2.0f * c2 + sqx) * (1.0f / 256.0f) - mu * mu;
    f32x2 rs;
    rs.x = rsqrtf(var.x + 1e-5f);
    rs.y = rsqrtf(var.y + 1e-5f);
    Ar[ti] = rs;
    Br[ti] = -rs * mu;
  }

  f32x2 o0[4] = {(f32x2){0.f, 0.f}, (f32x2){0.f, 0.f},
                 (f32x2){0.f, 0.f}, (f32x2){0.f, 0.f}};
  f32x2 o1[4] = {(f32x2){0.f, 0.f}, (f32x2){0.f, 0.f},
                 (f32x2){0.f, 0.f}, (f32x2){0.f, 0.f}};
  const int ebase = __builtin_amdgcn_readfirstlane(w * 64);
#pragma unroll 8
  for (int ei = 0; ei < 64; ++ei) {
    const int e = ebase + ei;
    const float4 gkw = *(const float4*)(g_GKW + 4 * e);           // s_load
    const f32x2 v2 = *(const f32x2*)(g_Vt + e * 128 + 2 * lane);  // coalesced
#pragma unroll
    for (int ti = 0; ti < 4; ++ti) {
      const float u = g_U[(bnt0 + ti) * 512 + e];  // wave-uniform s_load
      const f32x2 s = v2 + u;                                   // pk_add
      const f32x2 pre = Ar[ti] * s + (Br[ti] * gkw.x + gkw.y);  // pk_fma x2
      f32x2 y;
      y.x = fmaxf(pre.x, 0.f);
      y.y = fmaxf(pre.y, 0.f);
      o0[ti] += y * gkw.z;  // pk_fma
      o1[ti] += y * gkw.w;  // pk_fma
    }
  }

#pragma unroll
  for (int ti = 0; ti < 4; ++ti) {
    part[w][lane][ti * 4 + 0] = o0[ti].x;  // f even, ch0
    part[w][lane][ti * 4 + 1] = o1[ti].x;  // f even, ch1
    part[w][lane][ti * 4 + 2] = o0[ti].y;  // f odd,  ch0
    part[w][lane][ti * 4 + 3] = o1[ti].y;  // f odd,  ch1
  }
  __syncthreads();

  const int t = tid >> 7, f = tid & 127;
  const int m = f >> 1, ff = f & 1;
  float r0 = b2[0], r1 = b2[1];
#pragma unroll
  for (int w2 = 0; w2 < 8; ++w2) {
    r0 += part[w2][m][t * 4 + ff * 2 + 0];
    r1 += part[w2][m][t * 4 + ff * 2 + 1];
  }
  float2 res;
  res.x = r0;
  res.y = r1;
  *(float2*)(out + ((bnt0 + t) * 128 + f) * 2) = res;
}

// ---------------------------------------------------------------------------
extern "C" void kernel_launch(void* const* d_in, const int* in_sizes, int n_in,
                              void* d_out, int out_size, void* d_ws,
                              size_t ws_size, hipStream_t stream) {
  const float* x = (const float*)d_in[0];
  const float* t_emb = (const float*)d_in[1];
  const float* f_emb = (const float*)d_in[2];
  const float* ln_g = (const float*)d_in[3];
  const float* ln_b = (const float*)d_in[4];
  const float* W1 = (const float*)d_in[5];
  const float* b1 = (const float*)d_in[6];
  const float* W2 = (const float*)d_in[7];
  const float* b2 = (const float*)d_in[8];
  (void)d_ws; (void)ws_size;

  prep<<<600, 256, 0, stream>>>(x, t_emb, f_emb, ln_g, ln_b, W1, b1, W2);
  gemm3<<<170, 256, 0, stream>>>();
  decode2<<<512, 512, 0, stream>>>(b2, (float*)d_out);
}